// Round 5
// baseline (800.515 us; speedup 1.0000x reference)
//
#include <hip/hip_runtime.h>
#include <hip/hip_bf16.h>
#include <stdint.h>

// ---------------------------------------------------------------------------
// MHA forward, bf16 MFMA pipeline.
//   x[4,2048,1024] fp32; Wq/Wk/Wv/Wo [1024,1024] fp32; biases fp32.
//   out [4,2048,1024] fp32.
// ws layout (bytes):
//   [0,16M)   xb   : x as bf16 [8192][1024]  -> REUSED as Vt after gemm0
//   [16M,24M) wt   : Wq^T,Wk^T,Wv^T,Wo^T bf16, each [1024][1024]
//   [24M,40M) Qbh  : [64][2048][64] bf16 (scaled by 0.125*log2e)
//   [40M,56M) Kbh  : [64][2048][64] bf16
//   [56M,72M) Vbh  : [64][2048][64] bf16
//   [72M,88M) ctx  : [8192][1024] bf16
// Vt: [64 bh][64 d][2048 s'] bf16 where s' = s with bits 2<->3 swapped
//     (sigma baked in; PV pairing is then correct independent of the MFMA
//      input k-slot layout — the k-map cancels between A and B operands).
// attn (round 5): 2-wave blocks, split-t flash-decoding — wave w sweeps
// t in [w*1024,(w+1)*1024); LDS merge of (m,l,O) partials at the end.
// 4096 waves -> 4 waves/SIMD (was 2): TLP to cover softmax dependency stalls.
// ---------------------------------------------------------------------------

typedef __bf16 bf16;
typedef __bf16 bf16x8 __attribute__((ext_vector_type(8)));
typedef float  f32x4  __attribute__((ext_vector_type(4)));
typedef float  f32x16 __attribute__((ext_vector_type(16)));

#define XB_OFF   (0ull)
#define WT_OFF   (16ull << 20)
#define Q_OFF    (24ull << 20)
#define K_OFF    (40ull << 20)
#define V_OFF    (56ull << 20)
#define CTX_OFF  (72ull << 20)

// 1/sqrt(64) * log2(e), folded into Q so softmax uses exp2 directly.
#define QSCALE 0.18033688011112042591f

__device__ __forceinline__ void gload_lds16(const void* g, void* l) {
  __builtin_amdgcn_global_load_lds(
      (const __attribute__((address_space(1))) void*)g,
      (__attribute__((address_space(3))) void*)l, 16, 0, 0);
}

// --------------------------- fp32 -> bf16 x --------------------------------
__global__ __launch_bounds__(256) void cvt_x(const float* __restrict__ x,
                                             bf16* __restrict__ xb) {
  int i = blockIdx.x * 256 + threadIdx.x;          // one thread = 8 elements
  const float4* p = (const float4*)x;
  float4 a = p[(size_t)i * 2];
  float4 b = p[(size_t)i * 2 + 1];
  bf16x8 o;
  o[0] = (bf16)a.x; o[1] = (bf16)a.y; o[2] = (bf16)a.z; o[3] = (bf16)a.w;
  o[4] = (bf16)b.x; o[5] = (bf16)b.y; o[6] = (bf16)b.z; o[7] = (bf16)b.w;
  *((bf16x8*)xb + i) = o;
}

// ------------------- weight transpose + convert (W^T bf16) -----------------
__global__ __launch_bounds__(256) void cvt_w(const float* __restrict__ w0,
                                             const float* __restrict__ w1,
                                             const float* __restrict__ w2,
                                             const float* __restrict__ w3,
                                             bf16* __restrict__ wt) {
  int z = blockIdx.z;
  const float* W = (z == 0) ? w0 : (z == 1) ? w1 : (z == 2) ? w2 : w3;
  bf16* Wt = wt + (size_t)z * 1024 * 1024;
  __shared__ float tile[64][65];
  int i0 = blockIdx.y * 64, o0 = blockIdx.x * 64;
  int tid = threadIdx.x;
#pragma unroll
  for (int rep = 0; rep < 16; rep++) {
    int idx = rep * 256 + tid;
    int r = idx >> 6, c = idx & 63;
    tile[r][c] = W[(size_t)(i0 + r) * 1024 + o0 + c];
  }
  __syncthreads();
#pragma unroll
  for (int rep = 0; rep < 16; rep++) {
    int idx = rep * 256 + tid;
    int r = idx >> 6, c = idx & 63;
    Wt[(size_t)(o0 + r) * 1024 + i0 + c] = (bf16)tile[c][r];
  }
}

// --------------------------- NT bf16 GEMM ----------------------------------
// C[M,N] = A[M,1024] * Bt[N,1024]^T (+bias).  128x128 tile, BK=64, 4 waves.
// MODE 0: N=3072 fused QKV -> scatter to Qbh/Kbh/Vbh (Q scaled).
// MODE 1: N=1024 out-proj -> fp32 out.
template <int MODE>
__global__ __launch_bounds__(256, 2) void gemm_bt(
    const bf16* __restrict__ A, const bf16* __restrict__ Bt,
    const float* __restrict__ b0, const float* __restrict__ b1,
    const float* __restrict__ b2,
    bf16* __restrict__ Qo, bf16* __restrict__ Ko, bf16* __restrict__ Vo,
    float* __restrict__ out) {
  __shared__ __align__(16) bf16 a_lds[128 * 64];
  __shared__ __align__(16) bf16 b_lds[128 * 64];
  int tid = threadIdx.x;
  int lane = tid & 63, wid = tid >> 6;
  int wr = wid >> 1, wc = wid & 1;
  int g = lane >> 4, rlo = lane & 15;
  int m0 = blockIdx.x * 128, n0 = blockIdx.y * 128;

  f32x4 acc[4][4] = {};
  const char* Ab = (const char*)A;
  const char* Bb = (const char*)Bt;

  for (int k0 = 0; k0 < 1024; k0 += 64) {
#pragma unroll
    for (int rep = 0; rep < 4; rep++) {
      int idx = rep * 256 + tid;
      int row = idx >> 3;
      int sw = ((idx & 7) * 16) ^ ((row & 7) << 4);
      gload_lds16(Ab + ((size_t)(m0 + row) * 1024 + k0) * 2 + sw,
                  (char*)a_lds + (size_t)idx * 16);
    }
#pragma unroll
    for (int rep = 0; rep < 4; rep++) {
      int idx = rep * 256 + tid;
      int row = idx >> 3;
      int sw = ((idx & 7) * 16) ^ ((row & 7) << 4);
      gload_lds16(Bb + ((size_t)(n0 + row) * 1024 + k0) * 2 + sw,
                  (char*)b_lds + (size_t)idx * 16);
    }
    __syncthreads();
#pragma unroll
    for (int ks = 0; ks < 2; ks++) {
      bf16x8 af[4], bfr[4];
#pragma unroll
      for (int mt = 0; mt < 4; mt++) {
        int row = wr * 64 + mt * 16 + rlo;
        int koff = (ks * 32 + g * 8) ^ ((row & 7) << 3);
        af[mt] = *(const bf16x8*)&a_lds[row * 64 + koff];
      }
#pragma unroll
      for (int nt = 0; nt < 4; nt++) {
        int row = wc * 64 + nt * 16 + rlo;
        int koff = (ks * 32 + g * 8) ^ ((row & 7) << 3);
        bfr[nt] = *(const bf16x8*)&b_lds[row * 64 + koff];
      }
#pragma unroll
      for (int mt = 0; mt < 4; mt++)
#pragma unroll
        for (int nt = 0; nt < 4; nt++)
          acc[mt][nt] = __builtin_amdgcn_mfma_f32_16x16x32_bf16(
              af[mt], bfr[nt], acc[mt][nt], 0, 0, 0);
    }
    __syncthreads();
  }

#pragma unroll
  for (int nt = 0; nt < 4; nt++) {
    int n = n0 + wc * 64 + nt * 16 + rlo;
    if (MODE == 0) {
      int which = n >> 10, nn = n & 1023;
      const float* bp = (which == 0) ? b0 : (which == 1) ? b1 : b2;
      float bias = bp[nn];
      bf16* dst = (which == 0) ? Qo : (which == 1) ? Ko : Vo;
      float scale = (which == 0) ? QSCALE : 1.0f;
      int h = nn >> 6, hd = nn & 63;
#pragma unroll
      for (int mt = 0; mt < 4; mt++) {
#pragma unroll
        for (int r = 0; r < 4; r++) {
          int m = m0 + wr * 64 + mt * 16 + g * 4 + r;
          int bb = m >> 11, ss = m & 2047;
          float v = (acc[mt][nt][r] + bias) * scale;
          dst[(((size_t)(bb * 16 + h) * 2048 + ss) << 6) + hd] = (bf16)v;
        }
      }
    } else {
      float bias = b0[n];
#pragma unroll
      for (int mt = 0; mt < 4; mt++) {
#pragma unroll
        for (int r = 0; r < 4; r++) {
          int m = m0 + wr * 64 + mt * 16 + g * 4 + r;
          out[(size_t)m * 1024 + n] = acc[mt][nt][r] + bias;
        }
      }
    }
  }
}

// ----------------- V transpose with sigma permutation baked ----------------
// Vt[bh][d][s'] = V[bh][sigma(s')][d], sigma = swap bits 2<->3 (self-inverse).
__global__ __launch_bounds__(256) void vtr(const bf16* __restrict__ V,
                                           bf16* __restrict__ Vt) {
  __shared__ bf16 t[64][72];
  int bh = blockIdx.y, s0 = blockIdx.x * 64;
  int tid = threadIdx.x;
  const bf16* Vb = V + ((size_t)bh * 2048 + s0) * 64;
  bf16* Tb = Vt + (size_t)bh * 64 * 2048;
#pragma unroll
  for (int rep = 0; rep < 2; rep++) {
    int idx = rep * 256 + tid;
    int s = idx >> 3, dv = (idx & 7) * 8;
    bf16x8 v = *(const bf16x8*)&Vb[(size_t)s * 64 + dv];
#pragma unroll
    for (int j = 0; j < 8; j++) t[s][dv + j] = v[j];
  }
  __syncthreads();
#pragma unroll
  for (int rep = 0; rep < 2; rep++) {
    int idx = rep * 256 + tid;
    int d = idx >> 3, sc = (idx & 7) * 8;
    bf16x8 v;
#pragma unroll
    for (int j = 0; j < 8; j++) {
      int sl = sc + j;
      int sp = (sl & ~12) | ((sl & 4) << 1) | ((sl & 8) >> 1);  // sigma
      v[j] = t[sp][d];
    }
    *(bf16x8*)&Tb[(size_t)d * 2048 + s0 + sc] = v;
  }
}

// --------------------------- flash attention --------------------------------
// grid: 2048 x 128 threads. 2 waves per block; both waves own the same
// (bh, 64-row q-tile); wave w sweeps t in [w*1024,(w+1)*1024) (split-t).
// Swapped QK^T (mfma(K,Q)) -> lane owns one q-row (col = lane&31). K and V
// register-double-buffered. Epilogue: LDS merge of the two t-partials
// (m,l,O) then single write. [reg][lane] LDS layout -> conflict-free.
__global__ __launch_bounds__(128, 4) void attn(const bf16* __restrict__ Q,
                                               const bf16* __restrict__ K,
                                               const bf16* __restrict__ Vt,
                                               bf16* __restrict__ ctx) {
  __shared__ float sm_m[128];
  __shared__ float sm_l[128];
  __shared__ float sm_o[64 * 64];
  int tid = threadIdx.x;
  int lane = tid & 63, w = tid >> 6;
  int r31 = lane & 31, half = lane >> 5;
  // XCD-affine swizzle: blocks wg%8==c -> bh in [c*8,(c+1)*8): 4MB KV per XCD.
  int wg = blockIdx.x;
  int virt = (wg & 7) * 256 + (wg >> 3);
  int bh = virt >> 5, qt = virt & 31;  // 64-row q tile

  const bf16* qrowA = Q + ((size_t)bh * 2048 + qt * 64 + r31) * 64 + half * 8;
  const bf16* qrowB = qrowA + 32 * 64;
  const bf16* krow = K + ((size_t)bh * 2048 + r31) * 64 + half * 8;
  const bf16* vrow = Vt + ((size_t)bh * 64 + r31) * 2048 + half * 8;

  bf16x8 qa[4], qb[4];
#pragma unroll
  for (int ks = 0; ks < 4; ks++) {
    qa[ks] = *(const bf16x8*)&qrowA[ks * 16];
    qb[ks] = *(const bf16x8*)&qrowB[ks * 16];
  }

  f32x16 oa0 = {}, oa1 = {}, ob0 = {}, ob1 = {};
  float ma = -1e30f, la = 0.0f, mb = -1e30f, lb = 0.0f;

  int tstart = w * 1024, tend = tstart + 1024;

  // prime first tile of this wave's range into the register buffer
  bf16x8 kf[4], vf[4];
#pragma unroll
  for (int ks = 0; ks < 4; ks++)
    kf[ks] = *(const bf16x8*)&krow[(size_t)tstart * 64 + ks * 16];
  vf[0] = *(const bf16x8*)&vrow[tstart];
  vf[1] = *(const bf16x8*)&vrow[tstart + 16];
  vf[2] = *(const bf16x8*)&vrow[32 * 2048 + tstart];
  vf[3] = *(const bf16x8*)&vrow[32 * 2048 + tstart + 16];

#define SOFTMAX_BLOCK(S, M, L, O0, O1, P0, P1)                                \
  do {                                                                        \
    float pm = fmaxf(fmaxf(fmaxf(S[0], S[1]), fmaxf(S[2], S[3])),             \
                     fmaxf(fmaxf(S[4], S[5]), fmaxf(S[6], S[7])));            \
    float pm2 = fmaxf(fmaxf(fmaxf(S[8], S[9]), fmaxf(S[10], S[11])),          \
                      fmaxf(fmaxf(S[12], S[13]), fmaxf(S[14], S[15])));       \
    pm = fmaxf(pm, pm2);                                                      \
    pm = fmaxf(pm, __shfl_xor(pm, 32));                                       \
    if (!__all(pm - M <= 8.0f)) {                                             \
      float mn = fmaxf(M, pm);                                                \
      float scl = __builtin_amdgcn_exp2f(M - mn);                             \
      M = mn;                                                                 \
      L *= scl;                                                               \
      _Pragma("unroll") for (int r = 0; r < 16; r++) {                        \
        float sc = __shfl(scl, (r & 3) + 8 * (r >> 2) + 4 * half);            \
        O0[r] *= sc;                                                          \
        O1[r] *= sc;                                                          \
      }                                                                       \
    }                                                                         \
    _Pragma("unroll") for (int i = 0; i < 16; i++)                            \
        S[i] = __builtin_amdgcn_exp2f(S[i] - M);                              \
    float rs =                                                                \
        (((S[0] + S[1]) + (S[2] + S[3])) + ((S[4] + S[5]) + (S[6] + S[7]))) + \
        (((S[8] + S[9]) + (S[10] + S[11])) +                                  \
         ((S[12] + S[13]) + (S[14] + S[15])));                                \
    rs += __shfl_xor(rs, 32);                                                 \
    L += rs;                                                                  \
    _Pragma("unroll") for (int i = 0; i < 8; i++) {                           \
      P0[i] = (bf16)S[i];                                                     \
      P1[i] = (bf16)S[8 + i];                                                 \
    }                                                                         \
  } while (0)

#pragma unroll 2
  for (int t0 = tstart; t0 < tend; t0 += 32) {
    // issue next tile's loads first; they land while this tile computes.
    int t1 = tstart + ((t0 + 32 - tstart) & 1023);
    bf16x8 kn[4], vn[4];
#pragma unroll
    for (int ks = 0; ks < 4; ks++)
      kn[ks] = *(const bf16x8*)&krow[(size_t)t1 * 64 + ks * 16];
    vn[0] = *(const bf16x8*)&vrow[t1];
    vn[1] = *(const bf16x8*)&vrow[t1 + 16];
    vn[2] = *(const bf16x8*)&vrow[32 * 2048 + t1];
    vn[3] = *(const bf16x8*)&vrow[32 * 2048 + t1 + 16];

    // S^T[t][q]: col = lane&31 = q; row t = (reg&3)+8*(reg>>2)+4*half.
    f32x16 sa = {}, sb = {};
    __builtin_amdgcn_s_setprio(1);
#pragma unroll
    for (int ks = 0; ks < 4; ks++)
      sa = __builtin_amdgcn_mfma_f32_32x32x16_bf16(kf[ks], qa[ks], sa, 0, 0, 0);
#pragma unroll
    for (int ks = 0; ks < 4; ks++)
      sb = __builtin_amdgcn_mfma_f32_32x32x16_bf16(kf[ks], qb[ks], sb, 0, 0, 0);
    __builtin_amdgcn_s_setprio(0);

    bf16x8 paA0, paA1, paB0, paB1;
    SOFTMAX_BLOCK(sa, ma, la, oa0, oa1, paA0, paA1);
    SOFTMAX_BLOCK(sb, mb, lb, ob0, ob1, paB0, paB1);

    __builtin_amdgcn_s_setprio(1);
    oa0 = __builtin_amdgcn_mfma_f32_32x32x16_bf16(paA0, vf[0], oa0, 0, 0, 0);
    oa1 = __builtin_amdgcn_mfma_f32_32x32x16_bf16(paA0, vf[2], oa1, 0, 0, 0);
    oa0 = __builtin_amdgcn_mfma_f32_32x32x16_bf16(paA1, vf[1], oa0, 0, 0, 0);
    oa1 = __builtin_amdgcn_mfma_f32_32x32x16_bf16(paA1, vf[3], oa1, 0, 0, 0);
    ob0 = __builtin_amdgcn_mfma_f32_32x32x16_bf16(paB0, vf[0], ob0, 0, 0, 0);
    ob1 = __builtin_amdgcn_mfma_f32_32x32x16_bf16(paB0, vf[2], ob1, 0, 0, 0);
    ob0 = __builtin_amdgcn_mfma_f32_32x32x16_bf16(paB1, vf[1], ob0, 0, 0, 0);
    ob1 = __builtin_amdgcn_mfma_f32_32x32x16_bf16(paB1, vf[3], ob1, 0, 0, 0);
    __builtin_amdgcn_s_setprio(0);

    // rotate register buffers (renamed away by the unroll)
#pragma unroll
    for (int ks = 0; ks < 4; ks++) {
      kf[ks] = kn[ks];
      vf[ks] = vn[ks];
    }
  }
#undef SOFTMAX_BLOCK

  // ---- split-t merge: wave 1 dumps partials; wave 0 merges and writes ----
  if (w == 1) {
    sm_m[lane] = ma;
    sm_m[64 + lane] = mb;
    sm_l[lane] = la;
    sm_l[64 + lane] = lb;
#pragma unroll
    for (int r = 0; r < 16; r++) {
      sm_o[r * 64 + lane] = oa0[r];
      sm_o[(16 + r) * 64 + lane] = oa1[r];
      sm_o[(32 + r) * 64 + lane] = ob0[r];
      sm_o[(48 + r) * 64 + lane] = ob1[r];
    }
  }
  __syncthreads();
  if (w == 0) {
    float m1a = sm_m[lane], m1b = sm_m[64 + lane];
    float l1a = sm_l[lane], l1b = sm_l[64 + lane];
    float mma = fmaxf(ma, m1a), mmb = fmaxf(mb, m1b);
    float a0a = __builtin_amdgcn_exp2f(ma - mma);
    float a1a = __builtin_amdgcn_exp2f(m1a - mma);
    float a0b = __builtin_amdgcn_exp2f(mb - mmb);
    float a1b = __builtin_amdgcn_exp2f(m1b - mmb);
    float invA = 1.0f / (a0a * la + a1a * l1a);
    float invB = 1.0f / (a0b * lb + a1b * l1b);
    int b = bh >> 4, h = bh & 15;
#pragma unroll
    for (int r = 0; r < 16; r++) {
      int ql = (r & 3) + 8 * (r >> 2) + 4 * half;
      float s0a = __shfl(a0a, ql), s1a = __shfl(a1a, ql);
      float s0b = __shfl(a0b, ql), s1b = __shfl(a1b, ql);
      float iA = __shfl(invA, ql), iB = __shfl(invB, ql);
      float vA0 = s0a * oa0[r] + s1a * sm_o[r * 64 + lane];
      float vA1 = s0a * oa1[r] + s1a * sm_o[(16 + r) * 64 + lane];
      float vB0 = s0b * ob0[r] + s1b * sm_o[(32 + r) * 64 + lane];
      float vB1 = s0b * ob1[r] + s1b * sm_o[(48 + r) * 64 + lane];
      size_t baseA =
          (((size_t)(b * 2048 + qt * 64 + ql)) << 10) + h * 64 + r31;
      size_t baseB = baseA + (32ull << 10);
      ctx[baseA] = (bf16)(vA0 * iA);
      ctx[baseA + 32] = (bf16)(vA1 * iA);
      ctx[baseB] = (bf16)(vB0 * iB);
      ctx[baseB + 32] = (bf16)(vB1 * iB);
    }
  }
}

// ---------------------------------------------------------------------------
extern "C" void kernel_launch(void* const* d_in, const int* in_sizes, int n_in,
                              void* d_out, int out_size, void* d_ws, size_t ws_size,
                              hipStream_t stream) {
  const float* x  = (const float*)d_in[0];
  const float* Wq = (const float*)d_in[1];
  const float* bq = (const float*)d_in[2];
  const float* Wk = (const float*)d_in[3];
  const float* bk = (const float*)d_in[4];
  const float* Wv = (const float*)d_in[5];
  const float* bv = (const float*)d_in[6];
  const float* Wo = (const float*)d_in[7];
  const float* bo = (const float*)d_in[8];
  float* out = (float*)d_out;
  char* ws = (char*)d_ws;

  bf16* xb  = (bf16*)(ws + XB_OFF);
  bf16* wt  = (bf16*)(ws + WT_OFF);
  bf16* Qb  = (bf16*)(ws + Q_OFF);
  bf16* Kb  = (bf16*)(ws + K_OFF);
  bf16* Vb  = (bf16*)(ws + V_OFF);
  bf16* cx  = (bf16*)(ws + CTX_OFF);
  bf16* Vtb = (bf16*)(ws + XB_OFF);  // reuse xb region after gemm0

  cvt_x<<<4096, 256, 0, stream>>>(x, xb);
  cvt_w<<<dim3(16, 16, 4), 256, 0, stream>>>(Wq, Wk, Wv, Wo, wt);
  gemm_bt<0><<<dim3(64, 24), 256, 0, stream>>>(xb, wt, bq, bk, bv,
                                               Qb, Kb, Vb, nullptr);
  vtr<<<dim3(32, 64), 256, 0, stream>>>(Vb, Vtb);
  attn<<<2048, 128, 0, stream>>>(Qb, Kb, Vtb, cx);
  gemm_bt<1><<<dim3(64, 8), 256, 0, stream>>>(cx, wt + 3ull * 1024 * 1024, bo,
                                              nullptr, nullptr, nullptr,
                                              nullptr, nullptr, out);
}

// Round 6
// 224.243 us; speedup vs baseline: 3.5699x; 3.5699x over previous
//
#include <hip/hip_runtime.h>
#include <hip/hip_bf16.h>
#include <stdint.h>

// ---------------------------------------------------------------------------
// MHA forward, bf16 MFMA pipeline.
//   x[4,2048,1024] fp32; Wq/Wk/Wv/Wo [1024,1024] fp32; biases fp32.
//   out [4,2048,1024] fp32.
// ws layout (bytes):
//   [0,16M)   xb   : x as bf16 [8192][1024]  -> REUSED as Vt after gemm0
//   [16M,24M) wt   : Wq^T,Wk^T,Wv^T,Wo^T bf16, each [1024][1024]
//   [24M,40M) Qbh  : [64][2048][64] bf16 (scaled by 0.125*log2e)
//   [40M,56M) Kbh  : [64][2048][64] bf16
//   [56M,72M) Vbh  : [64][2048][64] bf16
//   [72M,88M) ctx  : [8192][1024] bf16
// Vt: [64 bh][64 d][2048 s'] bf16 where s' = s with bits 2<->3 swapped
//     (sigma baked in; PV pairing is then correct independent of the MFMA
//      input k-slot layout — the k-map cancels between A and B operands).
// attn (round 6): identical to round 5 EXCEPT __launch_bounds__(128,2).
// Round-5 post-mortem: (128,4) forced a 128-VGPR cap -> allocator clamped to
// 64 VGPR and spilled the f32x16 accumulators to scratch (3.28 GB HBM/dispatch,
// 56% of peak, MfmaUtil 3.8%). (128,2) lifts the cap; round-4's identical
// loop body compiled to 124 VGPR, so expect ~124-140 -> no spill, and the
// grid (4096 waves = 16/CU) supplies the TLP split-t was built for.
// ---------------------------------------------------------------------------

typedef __bf16 bf16;
typedef __bf16 bf16x8 __attribute__((ext_vector_type(8)));
typedef float  f32x4  __attribute__((ext_vector_type(4)));
typedef float  f32x16 __attribute__((ext_vector_type(16)));

#define XB_OFF   (0ull)
#define WT_OFF   (16ull << 20)
#define Q_OFF    (24ull << 20)
#define K_OFF    (40ull << 20)
#define V_OFF    (56ull << 20)
#define CTX_OFF  (72ull << 20)

// 1/sqrt(64) * log2(e), folded into Q so softmax uses exp2 directly.
#define QSCALE 0.18033688011112042591f

__device__ __forceinline__ void gload_lds16(const void* g, void* l) {
  __builtin_amdgcn_global_load_lds(
      (const __attribute__((address_space(1))) void*)g,
      (__attribute__((address_space(3))) void*)l, 16, 0, 0);
}

// --------------------------- fp32 -> bf16 x --------------------------------
__global__ __launch_bounds__(256) void cvt_x(const float* __restrict__ x,
                                             bf16* __restrict__ xb) {
  int i = blockIdx.x * 256 + threadIdx.x;          // one thread = 8 elements
  const float4* p = (const float4*)x;
  float4 a = p[(size_t)i * 2];
  float4 b = p[(size_t)i * 2 + 1];
  bf16x8 o;
  o[0] = (bf16)a.x; o[1] = (bf16)a.y; o[2] = (bf16)a.z; o[3] = (bf16)a.w;
  o[4] = (bf16)b.x; o[5] = (bf16)b.y; o[6] = (bf16)b.z; o[7] = (bf16)b.w;
  *((bf16x8*)xb + i) = o;
}

// ------------------- weight transpose + convert (W^T bf16) -----------------
__global__ __launch_bounds__(256) void cvt_w(const float* __restrict__ w0,
                                             const float* __restrict__ w1,
                                             const float* __restrict__ w2,
                                             const float* __restrict__ w3,
                                             bf16* __restrict__ wt) {
  int z = blockIdx.z;
  const float* W = (z == 0) ? w0 : (z == 1) ? w1 : (z == 2) ? w2 : w3;
  bf16* Wt = wt + (size_t)z * 1024 * 1024;
  __shared__ float tile[64][65];
  int i0 = blockIdx.y * 64, o0 = blockIdx.x * 64;
  int tid = threadIdx.x;
#pragma unroll
  for (int rep = 0; rep < 16; rep++) {
    int idx = rep * 256 + tid;
    int r = idx >> 6, c = idx & 63;
    tile[r][c] = W[(size_t)(i0 + r) * 1024 + o0 + c];
  }
  __syncthreads();
#pragma unroll
  for (int rep = 0; rep < 16; rep++) {
    int idx = rep * 256 + tid;
    int r = idx >> 6, c = idx & 63;
    Wt[(size_t)(o0 + r) * 1024 + i0 + c] = (bf16)tile[c][r];
  }
}

// --------------------------- NT bf16 GEMM ----------------------------------
// C[M,N] = A[M,1024] * Bt[N,1024]^T (+bias).  128x128 tile, BK=64, 4 waves.
// MODE 0: N=3072 fused QKV -> scatter to Qbh/Kbh/Vbh (Q scaled).
// MODE 1: N=1024 out-proj -> fp32 out.
template <int MODE>
__global__ __launch_bounds__(256, 2) void gemm_bt(
    const bf16* __restrict__ A, const bf16* __restrict__ Bt,
    const float* __restrict__ b0, const float* __restrict__ b1,
    const float* __restrict__ b2,
    bf16* __restrict__ Qo, bf16* __restrict__ Ko, bf16* __restrict__ Vo,
    float* __restrict__ out) {
  __shared__ __align__(16) bf16 a_lds[128 * 64];
  __shared__ __align__(16) bf16 b_lds[128 * 64];
  int tid = threadIdx.x;
  int lane = tid & 63, wid = tid >> 6;
  int wr = wid >> 1, wc = wid & 1;
  int g = lane >> 4, rlo = lane & 15;
  int m0 = blockIdx.x * 128, n0 = blockIdx.y * 128;

  f32x4 acc[4][4] = {};
  const char* Ab = (const char*)A;
  const char* Bb = (const char*)Bt;

  for (int k0 = 0; k0 < 1024; k0 += 64) {
#pragma unroll
    for (int rep = 0; rep < 4; rep++) {
      int idx = rep * 256 + tid;
      int row = idx >> 3;
      int sw = ((idx & 7) * 16) ^ ((row & 7) << 4);
      gload_lds16(Ab + ((size_t)(m0 + row) * 1024 + k0) * 2 + sw,
                  (char*)a_lds + (size_t)idx * 16);
    }
#pragma unroll
    for (int rep = 0; rep < 4; rep++) {
      int idx = rep * 256 + tid;
      int row = idx >> 3;
      int sw = ((idx & 7) * 16) ^ ((row & 7) << 4);
      gload_lds16(Bb + ((size_t)(n0 + row) * 1024 + k0) * 2 + sw,
                  (char*)b_lds + (size_t)idx * 16);
    }
    __syncthreads();
#pragma unroll
    for (int ks = 0; ks < 2; ks++) {
      bf16x8 af[4], bfr[4];
#pragma unroll
      for (int mt = 0; mt < 4; mt++) {
        int row = wr * 64 + mt * 16 + rlo;
        int koff = (ks * 32 + g * 8) ^ ((row & 7) << 3);
        af[mt] = *(const bf16x8*)&a_lds[row * 64 + koff];
      }
#pragma unroll
      for (int nt = 0; nt < 4; nt++) {
        int row = wc * 64 + nt * 16 + rlo;
        int koff = (ks * 32 + g * 8) ^ ((row & 7) << 3);
        bfr[nt] = *(const bf16x8*)&b_lds[row * 64 + koff];
      }
#pragma unroll
      for (int mt = 0; mt < 4; mt++)
#pragma unroll
        for (int nt = 0; nt < 4; nt++)
          acc[mt][nt] = __builtin_amdgcn_mfma_f32_16x16x32_bf16(
              af[mt], bfr[nt], acc[mt][nt], 0, 0, 0);
    }
    __syncthreads();
  }

#pragma unroll
  for (int nt = 0; nt < 4; nt++) {
    int n = n0 + wc * 64 + nt * 16 + rlo;
    if (MODE == 0) {
      int which = n >> 10, nn = n & 1023;
      const float* bp = (which == 0) ? b0 : (which == 1) ? b1 : b2;
      float bias = bp[nn];
      bf16* dst = (which == 0) ? Qo : (which == 1) ? Ko : Vo;
      float scale = (which == 0) ? QSCALE : 1.0f;
      int h = nn >> 6, hd = nn & 63;
#pragma unroll
      for (int mt = 0; mt < 4; mt++) {
#pragma unroll
        for (int r = 0; r < 4; r++) {
          int m = m0 + wr * 64 + mt * 16 + g * 4 + r;
          int bb = m >> 11, ss = m & 2047;
          float v = (acc[mt][nt][r] + bias) * scale;
          dst[(((size_t)(bb * 16 + h) * 2048 + ss) << 6) + hd] = (bf16)v;
        }
      }
    } else {
      float bias = b0[n];
#pragma unroll
      for (int mt = 0; mt < 4; mt++) {
#pragma unroll
        for (int r = 0; r < 4; r++) {
          int m = m0 + wr * 64 + mt * 16 + g * 4 + r;
          out[(size_t)m * 1024 + n] = acc[mt][nt][r] + bias;
        }
      }
    }
  }
}

// ----------------- V transpose with sigma permutation baked ----------------
// Vt[bh][d][s'] = V[bh][sigma(s')][d], sigma = swap bits 2<->3 (self-inverse).
__global__ __launch_bounds__(256) void vtr(const bf16* __restrict__ V,
                                           bf16* __restrict__ Vt) {
  __shared__ bf16 t[64][72];
  int bh = blockIdx.y, s0 = blockIdx.x * 64;
  int tid = threadIdx.x;
  const bf16* Vb = V + ((size_t)bh * 2048 + s0) * 64;
  bf16* Tb = Vt + (size_t)bh * 64 * 2048;
#pragma unroll
  for (int rep = 0; rep < 2; rep++) {
    int idx = rep * 256 + tid;
    int s = idx >> 3, dv = (idx & 7) * 8;
    bf16x8 v = *(const bf16x8*)&Vb[(size_t)s * 64 + dv];
#pragma unroll
    for (int j = 0; j < 8; j++) t[s][dv + j] = v[j];
  }
  __syncthreads();
#pragma unroll
  for (int rep = 0; rep < 2; rep++) {
    int idx = rep * 256 + tid;
    int d = idx >> 3, sc = (idx & 7) * 8;
    bf16x8 v;
#pragma unroll
    for (int j = 0; j < 8; j++) {
      int sl = sc + j;
      int sp = (sl & ~12) | ((sl & 4) << 1) | ((sl & 8) >> 1);  // sigma
      v[j] = t[sp][d];
    }
    *(bf16x8*)&Tb[(size_t)d * 2048 + s0 + sc] = v;
  }
}

// --------------------------- flash attention --------------------------------
// grid: 2048 x 128 threads. 2 waves per block; both waves own the same
// (bh, 64-row q-tile); wave w sweeps t in [w*1024,(w+1)*1024) (split-t).
// Swapped QK^T (mfma(K,Q)) -> lane owns one q-row (col = lane&31). K and V
// register-double-buffered. Epilogue: LDS merge of the two t-partials
// (m,l,O) then single write. [reg][lane] LDS layout -> conflict-free.
// launch_bounds(128,2): 256-VGPR cap. Do NOT tighten to (,4) — that forces
// accumulator spill to scratch (round-5: 3.28 GB HBM, 5x slowdown).
__global__ __launch_bounds__(128, 2) void attn(const bf16* __restrict__ Q,
                                               const bf16* __restrict__ K,
                                               const bf16* __restrict__ Vt,
                                               bf16* __restrict__ ctx) {
  __shared__ float sm_m[128];
  __shared__ float sm_l[128];
  __shared__ float sm_o[64 * 64];
  int tid = threadIdx.x;
  int lane = tid & 63, w = tid >> 6;
  int r31 = lane & 31, half = lane >> 5;
  // XCD-affine swizzle: blocks wg%8==c -> bh in [c*8,(c+1)*8): 4MB KV per XCD.
  int wg = blockIdx.x;
  int virt = (wg & 7) * 256 + (wg >> 3);
  int bh = virt >> 5, qt = virt & 31;  // 64-row q tile

  const bf16* qrowA = Q + ((size_t)bh * 2048 + qt * 64 + r31) * 64 + half * 8;
  const bf16* qrowB = qrowA + 32 * 64;
  const bf16* krow = K + ((size_t)bh * 2048 + r31) * 64 + half * 8;
  const bf16* vrow = Vt + ((size_t)bh * 64 + r31) * 2048 + half * 8;

  bf16x8 qa[4], qb[4];
#pragma unroll
  for (int ks = 0; ks < 4; ks++) {
    qa[ks] = *(const bf16x8*)&qrowA[ks * 16];
    qb[ks] = *(const bf16x8*)&qrowB[ks * 16];
  }

  f32x16 oa0 = {}, oa1 = {}, ob0 = {}, ob1 = {};
  float ma = -1e30f, la = 0.0f, mb = -1e30f, lb = 0.0f;

  int tstart = w * 1024, tend = tstart + 1024;

  // prime first tile of this wave's range into the register buffer
  bf16x8 kf[4], vf[4];
#pragma unroll
  for (int ks = 0; ks < 4; ks++)
    kf[ks] = *(const bf16x8*)&krow[(size_t)tstart * 64 + ks * 16];
  vf[0] = *(const bf16x8*)&vrow[tstart];
  vf[1] = *(const bf16x8*)&vrow[tstart + 16];
  vf[2] = *(const bf16x8*)&vrow[32 * 2048 + tstart];
  vf[3] = *(const bf16x8*)&vrow[32 * 2048 + tstart + 16];

#define SOFTMAX_BLOCK(S, M, L, O0, O1, P0, P1)                                \
  do {                                                                        \
    float pm = fmaxf(fmaxf(fmaxf(S[0], S[1]), fmaxf(S[2], S[3])),             \
                     fmaxf(fmaxf(S[4], S[5]), fmaxf(S[6], S[7])));            \
    float pm2 = fmaxf(fmaxf(fmaxf(S[8], S[9]), fmaxf(S[10], S[11])),          \
                      fmaxf(fmaxf(S[12], S[13]), fmaxf(S[14], S[15])));       \
    pm = fmaxf(pm, pm2);                                                      \
    pm = fmaxf(pm, __shfl_xor(pm, 32));                                       \
    if (!__all(pm - M <= 8.0f)) {                                             \
      float mn = fmaxf(M, pm);                                                \
      float scl = __builtin_amdgcn_exp2f(M - mn);                             \
      M = mn;                                                                 \
      L *= scl;                                                               \
      _Pragma("unroll") for (int r = 0; r < 16; r++) {                        \
        float sc = __shfl(scl, (r & 3) + 8 * (r >> 2) + 4 * half);            \
        O0[r] *= sc;                                                          \
        O1[r] *= sc;                                                          \
      }                                                                       \
    }                                                                         \
    _Pragma("unroll") for (int i = 0; i < 16; i++)                            \
        S[i] = __builtin_amdgcn_exp2f(S[i] - M);                              \
    float rs =                                                                \
        (((S[0] + S[1]) + (S[2] + S[3])) + ((S[4] + S[5]) + (S[6] + S[7]))) + \
        (((S[8] + S[9]) + (S[10] + S[11])) +                                  \
         ((S[12] + S[13]) + (S[14] + S[15])));                                \
    rs += __shfl_xor(rs, 32);                                                 \
    L += rs;                                                                  \
    _Pragma("unroll") for (int i = 0; i < 8; i++) {                           \
      P0[i] = (bf16)S[i];                                                     \
      P1[i] = (bf16)S[8 + i];                                                 \
    }                                                                         \
  } while (0)

#pragma unroll 2
  for (int t0 = tstart; t0 < tend; t0 += 32) {
    // issue next tile's loads first; they land while this tile computes.
    int t1 = tstart + ((t0 + 32 - tstart) & 1023);
    bf16x8 kn[4], vn[4];
#pragma unroll
    for (int ks = 0; ks < 4; ks++)
      kn[ks] = *(const bf16x8*)&krow[(size_t)t1 * 64 + ks * 16];
    vn[0] = *(const bf16x8*)&vrow[t1];
    vn[1] = *(const bf16x8*)&vrow[t1 + 16];
    vn[2] = *(const bf16x8*)&vrow[32 * 2048 + t1];
    vn[3] = *(const bf16x8*)&vrow[32 * 2048 + t1 + 16];

    // S^T[t][q]: col = lane&31 = q; row t = (reg&3)+8*(reg>>2)+4*half.
    f32x16 sa = {}, sb = {};
    __builtin_amdgcn_s_setprio(1);
#pragma unroll
    for (int ks = 0; ks < 4; ks++)
      sa = __builtin_amdgcn_mfma_f32_32x32x16_bf16(kf[ks], qa[ks], sa, 0, 0, 0);
#pragma unroll
    for (int ks = 0; ks < 4; ks++)
      sb = __builtin_amdgcn_mfma_f32_32x32x16_bf16(kf[ks], qb[ks], sb, 0, 0, 0);
    __builtin_amdgcn_s_setprio(0);

    bf16x8 paA0, paA1, paB0, paB1;
    SOFTMAX_BLOCK(sa, ma, la, oa0, oa1, paA0, paA1);
    SOFTMAX_BLOCK(sb, mb, lb, ob0, ob1, paB0, paB1);

    __builtin_amdgcn_s_setprio(1);
    oa0 = __builtin_amdgcn_mfma_f32_32x32x16_bf16(paA0, vf[0], oa0, 0, 0, 0);
    oa1 = __builtin_amdgcn_mfma_f32_32x32x16_bf16(paA0, vf[2], oa1, 0, 0, 0);
    oa0 = __builtin_amdgcn_mfma_f32_32x32x16_bf16(paA1, vf[1], oa0, 0, 0, 0);
    oa1 = __builtin_amdgcn_mfma_f32_32x32x16_bf16(paA1, vf[3], oa1, 0, 0, 0);
    ob0 = __builtin_amdgcn_mfma_f32_32x32x16_bf16(paB0, vf[0], ob0, 0, 0, 0);
    ob1 = __builtin_amdgcn_mfma_f32_32x32x16_bf16(paB0, vf[2], ob1, 0, 0, 0);
    ob0 = __builtin_amdgcn_mfma_f32_32x32x16_bf16(paB1, vf[1], ob0, 0, 0, 0);
    ob1 = __builtin_amdgcn_mfma_f32_32x32x16_bf16(paB1, vf[3], ob1, 0, 0, 0);
    __builtin_amdgcn_s_setprio(0);

    // rotate register buffers (renamed away by the unroll)
#pragma unroll
    for (int ks = 0; ks < 4; ks++) {
      kf[ks] = kn[ks];
      vf[ks] = vn[ks];
    }
  }
#undef SOFTMAX_BLOCK

  // ---- split-t merge: wave 1 dumps partials; wave 0 merges and writes ----
  if (w == 1) {
    sm_m[lane] = ma;
    sm_m[64 + lane] = mb;
    sm_l[lane] = la;
    sm_l[64 + lane] = lb;
#pragma unroll
    for (int r = 0; r < 16; r++) {
      sm_o[r * 64 + lane] = oa0[r];
      sm_o[(16 + r) * 64 + lane] = oa1[r];
      sm_o[(32 + r) * 64 + lane] = ob0[r];
      sm_o[(48 + r) * 64 + lane] = ob1[r];
    }
  }
  __syncthreads();
  if (w == 0) {
    float m1a = sm_m[lane], m1b = sm_m[64 + lane];
    float l1a = sm_l[lane], l1b = sm_l[64 + lane];
    float mma = fmaxf(ma, m1a), mmb = fmaxf(mb, m1b);
    float a0a = __builtin_amdgcn_exp2f(ma - mma);
    float a1a = __builtin_amdgcn_exp2f(m1a - mma);
    float a0b = __builtin_amdgcn_exp2f(mb - mmb);
    float a1b = __builtin_amdgcn_exp2f(m1b - mmb);
    float invA = 1.0f / (a0a * la + a1a * l1a);
    float invB = 1.0f / (a0b * lb + a1b * l1b);
    int b = bh >> 4, h = bh & 15;
#pragma unroll
    for (int r = 0; r < 16; r++) {
      int ql = (r & 3) + 8 * (r >> 2) + 4 * half;
      float s0a = __shfl(a0a, ql), s1a = __shfl(a1a, ql);
      float s0b = __shfl(a0b, ql), s1b = __shfl(a1b, ql);
      float iA = __shfl(invA, ql), iB = __shfl(invB, ql);
      float vA0 = s0a * oa0[r] + s1a * sm_o[r * 64 + lane];
      float vA1 = s0a * oa1[r] + s1a * sm_o[(16 + r) * 64 + lane];
      float vB0 = s0b * ob0[r] + s1b * sm_o[(32 + r) * 64 + lane];
      float vB1 = s0b * ob1[r] + s1b * sm_o[(48 + r) * 64 + lane];
      size_t baseA =
          (((size_t)(b * 2048 + qt * 64 + ql)) << 10) + h * 64 + r31;
      size_t baseB = baseA + (32ull << 10);
      ctx[baseA] = (bf16)(vA0 * iA);
      ctx[baseA + 32] = (bf16)(vA1 * iA);
      ctx[baseB] = (bf16)(vB0 * iB);
      ctx[baseB + 32] = (bf16)(vB1 * iB);
    }
  }
}

// ---------------------------------------------------------------------------
extern "C" void kernel_launch(void* const* d_in, const int* in_sizes, int n_in,
                              void* d_out, int out_size, void* d_ws, size_t ws_size,
                              hipStream_t stream) {
  const float* x  = (const float*)d_in[0];
  const float* Wq = (const float*)d_in[1];
  const float* bq = (const float*)d_in[2];
  const float* Wk = (const float*)d_in[3];
  const float* bk = (const float*)d_in[4];
  const float* Wv = (const float*)d_in[5];
  const float* bv = (const float*)d_in[6];
  const float* Wo = (const float*)d_in[7];
  const float* bo = (const float*)d_in[8];
  float* out = (float*)d_out;
  char* ws = (char*)d_ws;

  bf16* xb  = (bf16*)(ws + XB_OFF);
  bf16* wt  = (bf16*)(ws + WT_OFF);
  bf16* Qb  = (bf16*)(ws + Q_OFF);
  bf16* Kb  = (bf16*)(ws + K_OFF);
  bf16* Vb  = (bf16*)(ws + V_OFF);
  bf16* cx  = (bf16*)(ws + CTX_OFF);
  bf16* Vtb = (bf16*)(ws + XB_OFF);  // reuse xb region after gemm0

  cvt_x<<<4096, 256, 0, stream>>>(x, xb);
  cvt_w<<<dim3(16, 16, 4), 256, 0, stream>>>(Wq, Wk, Wv, Wo, wt);
  gemm_bt<0><<<dim3(64, 24), 256, 0, stream>>>(xb, wt, bq, bk, bv,
                                               Qb, Kb, Vb, nullptr);
  vtr<<<dim3(32, 64), 256, 0, stream>>>(Vb, Vtb);
  attn<<<2048, 128, 0, stream>>>(Qb, Kb, Vtb, cx);
  gemm_bt<1><<<dim3(64, 8), 256, 0, stream>>>(cx, wt + 3ull * 1024 * 1024, bo,
                                              nullptr, nullptr, nullptr,
                                              nullptr, nullptr, out);
}

// Round 7
// 219.487 us; speedup vs baseline: 3.6472x; 1.0217x over previous
//
#include <hip/hip_runtime.h>
#include <hip/hip_bf16.h>
#include <stdint.h>

// ---------------------------------------------------------------------------
// MHA forward, bf16 MFMA pipeline.
//   x[4,2048,1024] fp32; Wq/Wk/Wv/Wo [1024,1024] fp32; biases fp32.
//   out [4,2048,1024] fp32.
// ws layout (bytes):
//   [0,16M)   xb   : x as bf16 [8192][1024]  -> REUSED as Vt after gemm0
//   [16M,24M) wt   : Wq^T,Wk^T,Wv^T,Wo^T bf16, each [1024][1024]
//   [24M,40M) Qbh  : [64][2048][64] bf16 (scaled by 0.125*log2e)
//   [40M,56M) Kbh  : [64][2048][64] bf16
//   [56M,72M) Vbh  : [64][2048][64] bf16
//   [72M,88M) ctx  : [8192][1024] bf16
// Vt: [64 bh][64 d][2048 s'] bf16, s' = s with bits 2<->3 swapped.
// attn (round 7): same per-wave loop as round 6, but packed 4 waves/block
// (256 threads = 2 q-subtiles x 2 t-halves, split-t merge per pair).
// Evidence R1-R6: resident waves scale with workgroup size (256-thr blocks
// reached 11-13 waves/CU; 64/128-thr blocks stuck at ~6). Grid 1024 blocks
// = 4 blocks/CU = 16 waves/CU supplied. VGPR ~120 (4/SIMD allowed).
// ---------------------------------------------------------------------------

typedef __bf16 bf16;
typedef __bf16 bf16x8 __attribute__((ext_vector_type(8)));
typedef float  f32x4  __attribute__((ext_vector_type(4)));
typedef float  f32x16 __attribute__((ext_vector_type(16)));

#define XB_OFF   (0ull)
#define WT_OFF   (16ull << 20)
#define Q_OFF    (24ull << 20)
#define K_OFF    (40ull << 20)
#define V_OFF    (56ull << 20)
#define CTX_OFF  (72ull << 20)

// 1/sqrt(64) * log2(e), folded into Q so softmax uses exp2 directly.
#define QSCALE 0.18033688011112042591f

__device__ __forceinline__ void gload_lds16(const void* g, void* l) {
  __builtin_amdgcn_global_load_lds(
      (const __attribute__((address_space(1))) void*)g,
      (__attribute__((address_space(3))) void*)l, 16, 0, 0);
}

// --------------------------- fp32 -> bf16 x --------------------------------
__global__ __launch_bounds__(256) void cvt_x(const float* __restrict__ x,
                                             bf16* __restrict__ xb) {
  int i = blockIdx.x * 256 + threadIdx.x;          // one thread = 8 elements
  const float4* p = (const float4*)x;
  float4 a = p[(size_t)i * 2];
  float4 b = p[(size_t)i * 2 + 1];
  bf16x8 o;
  o[0] = (bf16)a.x; o[1] = (bf16)a.y; o[2] = (bf16)a.z; o[3] = (bf16)a.w;
  o[4] = (bf16)b.x; o[5] = (bf16)b.y; o[6] = (bf16)b.z; o[7] = (bf16)b.w;
  *((bf16x8*)xb + i) = o;
}

// ------------------- weight transpose + convert (W^T bf16) -----------------
__global__ __launch_bounds__(256) void cvt_w(const float* __restrict__ w0,
                                             const float* __restrict__ w1,
                                             const float* __restrict__ w2,
                                             const float* __restrict__ w3,
                                             bf16* __restrict__ wt) {
  int z = blockIdx.z;
  const float* W = (z == 0) ? w0 : (z == 1) ? w1 : (z == 2) ? w2 : w3;
  bf16* Wt = wt + (size_t)z * 1024 * 1024;
  __shared__ float tile[64][65];
  int i0 = blockIdx.y * 64, o0 = blockIdx.x * 64;
  int tid = threadIdx.x;
#pragma unroll
  for (int rep = 0; rep < 16; rep++) {
    int idx = rep * 256 + tid;
    int r = idx >> 6, c = idx & 63;
    tile[r][c] = W[(size_t)(i0 + r) * 1024 + o0 + c];
  }
  __syncthreads();
#pragma unroll
  for (int rep = 0; rep < 16; rep++) {
    int idx = rep * 256 + tid;
    int r = idx >> 6, c = idx & 63;
    Wt[(size_t)(o0 + r) * 1024 + i0 + c] = (bf16)tile[c][r];
  }
}

// --------------------------- NT bf16 GEMM ----------------------------------
// C[M,N] = A[M,1024] * Bt[N,1024]^T (+bias).  128x128 tile, BK=64, 4 waves.
// MODE 0: N=3072 fused QKV -> scatter to Qbh/Kbh/Vbh (Q scaled).
// MODE 1: N=1024 out-proj -> fp32 out.
template <int MODE>
__global__ __launch_bounds__(256, 2) void gemm_bt(
    const bf16* __restrict__ A, const bf16* __restrict__ Bt,
    const float* __restrict__ b0, const float* __restrict__ b1,
    const float* __restrict__ b2,
    bf16* __restrict__ Qo, bf16* __restrict__ Ko, bf16* __restrict__ Vo,
    float* __restrict__ out) {
  __shared__ __align__(16) bf16 a_lds[128 * 64];
  __shared__ __align__(16) bf16 b_lds[128 * 64];
  int tid = threadIdx.x;
  int lane = tid & 63, wid = tid >> 6;
  int wr = wid >> 1, wc = wid & 1;
  int g = lane >> 4, rlo = lane & 15;
  int m0 = blockIdx.x * 128, n0 = blockIdx.y * 128;

  f32x4 acc[4][4] = {};
  const char* Ab = (const char*)A;
  const char* Bb = (const char*)Bt;

  for (int k0 = 0; k0 < 1024; k0 += 64) {
#pragma unroll
    for (int rep = 0; rep < 4; rep++) {
      int idx = rep * 256 + tid;
      int row = idx >> 3;
      int sw = ((idx & 7) * 16) ^ ((row & 7) << 4);
      gload_lds16(Ab + ((size_t)(m0 + row) * 1024 + k0) * 2 + sw,
                  (char*)a_lds + (size_t)idx * 16);
    }
#pragma unroll
    for (int rep = 0; rep < 4; rep++) {
      int idx = rep * 256 + tid;
      int row = idx >> 3;
      int sw = ((idx & 7) * 16) ^ ((row & 7) << 4);
      gload_lds16(Bb + ((size_t)(n0 + row) * 1024 + k0) * 2 + sw,
                  (char*)b_lds + (size_t)idx * 16);
    }
    __syncthreads();
#pragma unroll
    for (int ks = 0; ks < 2; ks++) {
      bf16x8 af[4], bfr[4];
#pragma unroll
      for (int mt = 0; mt < 4; mt++) {
        int row = wr * 64 + mt * 16 + rlo;
        int koff = (ks * 32 + g * 8) ^ ((row & 7) << 3);
        af[mt] = *(const bf16x8*)&a_lds[row * 64 + koff];
      }
#pragma unroll
      for (int nt = 0; nt < 4; nt++) {
        int row = wc * 64 + nt * 16 + rlo;
        int koff = (ks * 32 + g * 8) ^ ((row & 7) << 3);
        bfr[nt] = *(const bf16x8*)&b_lds[row * 64 + koff];
      }
#pragma unroll
      for (int mt = 0; mt < 4; mt++)
#pragma unroll
        for (int nt = 0; nt < 4; nt++)
          acc[mt][nt] = __builtin_amdgcn_mfma_f32_16x16x32_bf16(
              af[mt], bfr[nt], acc[mt][nt], 0, 0, 0);
    }
    __syncthreads();
  }

#pragma unroll
  for (int nt = 0; nt < 4; nt++) {
    int n = n0 + wc * 64 + nt * 16 + rlo;
    if (MODE == 0) {
      int which = n >> 10, nn = n & 1023;
      const float* bp = (which == 0) ? b0 : (which == 1) ? b1 : b2;
      float bias = bp[nn];
      bf16* dst = (which == 0) ? Qo : (which == 1) ? Ko : Vo;
      float scale = (which == 0) ? QSCALE : 1.0f;
      int h = nn >> 6, hd = nn & 63;
#pragma unroll
      for (int mt = 0; mt < 4; mt++) {
#pragma unroll
        for (int r = 0; r < 4; r++) {
          int m = m0 + wr * 64 + mt * 16 + g * 4 + r;
          int bb = m >> 11, ss = m & 2047;
          float v = (acc[mt][nt][r] + bias) * scale;
          dst[(((size_t)(bb * 16 + h) * 2048 + ss) << 6) + hd] = (bf16)v;
        }
      }
    } else {
      float bias = b0[n];
#pragma unroll
      for (int mt = 0; mt < 4; mt++) {
#pragma unroll
        for (int r = 0; r < 4; r++) {
          int m = m0 + wr * 64 + mt * 16 + g * 4 + r;
          out[(size_t)m * 1024 + n] = acc[mt][nt][r] + bias;
        }
      }
    }
  }
}

// ----------------- V transpose with sigma permutation baked ----------------
// Vt[bh][d][s'] = V[bh][sigma(s')][d], sigma = swap bits 2<->3 (self-inverse).
__global__ __launch_bounds__(256) void vtr(const bf16* __restrict__ V,
                                           bf16* __restrict__ Vt) {
  __shared__ bf16 t[64][72];
  int bh = blockIdx.y, s0 = blockIdx.x * 64;
  int tid = threadIdx.x;
  const bf16* Vb = V + ((size_t)bh * 2048 + s0) * 64;
  bf16* Tb = Vt + (size_t)bh * 64 * 2048;
#pragma unroll
  for (int rep = 0; rep < 2; rep++) {
    int idx = rep * 256 + tid;
    int s = idx >> 3, dv = (idx & 7) * 8;
    bf16x8 v = *(const bf16x8*)&Vb[(size_t)s * 64 + dv];
#pragma unroll
    for (int j = 0; j < 8; j++) t[s][dv + j] = v[j];
  }
  __syncthreads();
#pragma unroll
  for (int rep = 0; rep < 2; rep++) {
    int idx = rep * 256 + tid;
    int d = idx >> 3, sc = (idx & 7) * 8;
    bf16x8 v;
#pragma unroll
    for (int j = 0; j < 8; j++) {
      int sl = sc + j;
      int sp = (sl & ~12) | ((sl & 4) << 1) | ((sl & 8) >> 1);  // sigma
      v[j] = t[sp][d];
    }
    *(bf16x8*)&Tb[(size_t)d * 2048 + s0 + sc] = v;
  }
}

// --------------------------- flash attention --------------------------------
// grid: 1024 x 256 threads. 4 waves/block = 2 q-subtiles x 2 t-halves.
// Each wave: 64 q-rows (2x32 blocks), t in [th*1024,(th+1)*1024) (split-t).
// Swapped QK^T (mfma(K,Q)) -> lane owns one q-row (col = lane&31). K and V
// register-double-buffered. Per q-subtile pair: LDS merge of two t-partials.
// launch_bounds(256,2): 256-VGPR cap. Do NOT tighten — forces spill (R5).
__global__ __launch_bounds__(256, 2) void attn(const bf16* __restrict__ Q,
                                               const bf16* __restrict__ K,
                                               const bf16* __restrict__ Vt,
                                               bf16* __restrict__ ctx) {
  __shared__ float sm_m[2][128];
  __shared__ float sm_l[2][128];
  __shared__ float sm_o[2][64 * 64];
  int tid = threadIdx.x;
  int lane = tid & 63, w = tid >> 6;
  int qsub = w >> 1, th = w & 1;
  int r31 = lane & 31, half = lane >> 5;
  // XCD-affine swizzle: 1024 blocks, XCD c gets virt [c*128,(c+1)*128)
  // -> bh in [c*8,(c+1)*8): 4MB KV per XCD L2.
  int wg = blockIdx.x;
  int virt = (wg & 7) * 128 + (wg >> 3);
  int bh = virt >> 4, qt = virt & 15;  // 128-row q tile per block
  int qbase = qt * 128 + qsub * 64;

  const bf16* qrowA = Q + ((size_t)bh * 2048 + qbase + r31) * 64 + half * 8;
  const bf16* qrowB = qrowA + 32 * 64;
  const bf16* krow = K + ((size_t)bh * 2048 + r31) * 64 + half * 8;
  const bf16* vrow = Vt + ((size_t)bh * 64 + r31) * 2048 + half * 8;

  bf16x8 qa[4], qb[4];
#pragma unroll
  for (int ks = 0; ks < 4; ks++) {
    qa[ks] = *(const bf16x8*)&qrowA[ks * 16];
    qb[ks] = *(const bf16x8*)&qrowB[ks * 16];
  }

  f32x16 oa0 = {}, oa1 = {}, ob0 = {}, ob1 = {};
  float ma = -1e30f, la = 0.0f, mb = -1e30f, lb = 0.0f;

  int tstart = th * 1024, tend = tstart + 1024;

  // prime first tile of this wave's range into the register buffer
  bf16x8 kf[4], vf[4];
#pragma unroll
  for (int ks = 0; ks < 4; ks++)
    kf[ks] = *(const bf16x8*)&krow[(size_t)tstart * 64 + ks * 16];
  vf[0] = *(const bf16x8*)&vrow[tstart];
  vf[1] = *(const bf16x8*)&vrow[tstart + 16];
  vf[2] = *(const bf16x8*)&vrow[32 * 2048 + tstart];
  vf[3] = *(const bf16x8*)&vrow[32 * 2048 + tstart + 16];

#define SOFTMAX_BLOCK(S, M, L, O0, O1, P0, P1)                                \
  do {                                                                        \
    float pm = fmaxf(fmaxf(fmaxf(S[0], S[1]), fmaxf(S[2], S[3])),             \
                     fmaxf(fmaxf(S[4], S[5]), fmaxf(S[6], S[7])));            \
    float pm2 = fmaxf(fmaxf(fmaxf(S[8], S[9]), fmaxf(S[10], S[11])),          \
                      fmaxf(fmaxf(S[12], S[13]), fmaxf(S[14], S[15])));       \
    pm = fmaxf(pm, pm2);                                                      \
    pm = fmaxf(pm, __shfl_xor(pm, 32));                                       \
    if (!__all(pm - M <= 8.0f)) {                                             \
      float mn = fmaxf(M, pm);                                                \
      float scl = __builtin_amdgcn_exp2f(M - mn);                             \
      M = mn;                                                                 \
      L *= scl;                                                               \
      _Pragma("unroll") for (int r = 0; r < 16; r++) {                        \
        float sc = __shfl(scl, (r & 3) + 8 * (r >> 2) + 4 * half);            \
        O0[r] *= sc;                                                          \
        O1[r] *= sc;                                                          \
      }                                                                       \
    }                                                                         \
    _Pragma("unroll") for (int i = 0; i < 16; i++)                            \
        S[i] = __builtin_amdgcn_exp2f(S[i] - M);                              \
    float rs =                                                                \
        (((S[0] + S[1]) + (S[2] + S[3])) + ((S[4] + S[5]) + (S[6] + S[7]))) + \
        (((S[8] + S[9]) + (S[10] + S[11])) +                                  \
         ((S[12] + S[13]) + (S[14] + S[15])));                                \
    rs += __shfl_xor(rs, 32);                                                 \
    L += rs;                                                                  \
    _Pragma("unroll") for (int i = 0; i < 8; i++) {                           \
      P0[i] = (bf16)S[i];                                                     \
      P1[i] = (bf16)S[8 + i];                                                 \
    }                                                                         \
  } while (0)

#pragma unroll 2
  for (int t0 = tstart; t0 < tend; t0 += 32) {
    // issue next tile's loads first; they land while this tile computes.
    int t1 = tstart + ((t0 + 32 - tstart) & 1023);
    bf16x8 kn[4], vn[4];
#pragma unroll
    for (int ks = 0; ks < 4; ks++)
      kn[ks] = *(const bf16x8*)&krow[(size_t)t1 * 64 + ks * 16];
    vn[0] = *(const bf16x8*)&vrow[t1];
    vn[1] = *(const bf16x8*)&vrow[t1 + 16];
    vn[2] = *(const bf16x8*)&vrow[32 * 2048 + t1];
    vn[3] = *(const bf16x8*)&vrow[32 * 2048 + t1 + 16];

    // S^T[t][q]: col = lane&31 = q; row t = (reg&3)+8*(reg>>2)+4*half.
    f32x16 sa = {}, sb = {};
    __builtin_amdgcn_s_setprio(1);
#pragma unroll
    for (int ks = 0; ks < 4; ks++)
      sa = __builtin_amdgcn_mfma_f32_32x32x16_bf16(kf[ks], qa[ks], sa, 0, 0, 0);
#pragma unroll
    for (int ks = 0; ks < 4; ks++)
      sb = __builtin_amdgcn_mfma_f32_32x32x16_bf16(kf[ks], qb[ks], sb, 0, 0, 0);
    __builtin_amdgcn_s_setprio(0);

    bf16x8 paA0, paA1, paB0, paB1;
    SOFTMAX_BLOCK(sa, ma, la, oa0, oa1, paA0, paA1);
    SOFTMAX_BLOCK(sb, mb, lb, ob0, ob1, paB0, paB1);

    __builtin_amdgcn_s_setprio(1);
    oa0 = __builtin_amdgcn_mfma_f32_32x32x16_bf16(paA0, vf[0], oa0, 0, 0, 0);
    oa1 = __builtin_amdgcn_mfma_f32_32x32x16_bf16(paA0, vf[2], oa1, 0, 0, 0);
    oa0 = __builtin_amdgcn_mfma_f32_32x32x16_bf16(paA1, vf[1], oa0, 0, 0, 0);
    oa1 = __builtin_amdgcn_mfma_f32_32x32x16_bf16(paA1, vf[3], oa1, 0, 0, 0);
    ob0 = __builtin_amdgcn_mfma_f32_32x32x16_bf16(paB0, vf[0], ob0, 0, 0, 0);
    ob1 = __builtin_amdgcn_mfma_f32_32x32x16_bf16(paB0, vf[2], ob1, 0, 0, 0);
    ob0 = __builtin_amdgcn_mfma_f32_32x32x16_bf16(paB1, vf[1], ob0, 0, 0, 0);
    ob1 = __builtin_amdgcn_mfma_f32_32x32x16_bf16(paB1, vf[3], ob1, 0, 0, 0);
    __builtin_amdgcn_s_setprio(0);

    // rotate register buffers (renamed away by the unroll)
#pragma unroll
    for (int ks = 0; ks < 4; ks++) {
      kf[ks] = kn[ks];
      vf[ks] = vn[ks];
    }
  }
#undef SOFTMAX_BLOCK

  // ---- split-t merge per q-subtile: t-half 1 dumps; t-half 0 merges ----
  if (th == 1) {
    sm_m[qsub][lane] = ma;
    sm_m[qsub][64 + lane] = mb;
    sm_l[qsub][lane] = la;
    sm_l[qsub][64 + lane] = lb;
#pragma unroll
    for (int r = 0; r < 16; r++) {
      sm_o[qsub][r * 64 + lane] = oa0[r];
      sm_o[qsub][(16 + r) * 64 + lane] = oa1[r];
      sm_o[qsub][(32 + r) * 64 + lane] = ob0[r];
      sm_o[qsub][(48 + r) * 64 + lane] = ob1[r];
    }
  }
  __syncthreads();
  if (th == 0) {
    float m1a = sm_m[qsub][lane], m1b = sm_m[qsub][64 + lane];
    float l1a = sm_l[qsub][lane], l1b = sm_l[qsub][64 + lane];
    float mma = fmaxf(ma, m1a), mmb = fmaxf(mb, m1b);
    float a0a = __builtin_amdgcn_exp2f(ma - mma);
    float a1a = __builtin_amdgcn_exp2f(m1a - mma);
    float a0b = __builtin_amdgcn_exp2f(mb - mmb);
    float a1b = __builtin_amdgcn_exp2f(m1b - mmb);
    float invA = 1.0f / (a0a * la + a1a * l1a);
    float invB = 1.0f / (a0b * lb + a1b * l1b);
    int b = bh >> 4, h = bh & 15;
#pragma unroll
    for (int r = 0; r < 16; r++) {
      int ql = (r & 3) + 8 * (r >> 2) + 4 * half;
      float s0a = __shfl(a0a, ql), s1a = __shfl(a1a, ql);
      float s0b = __shfl(a0b, ql), s1b = __shfl(a1b, ql);
      float iA = __shfl(invA, ql), iB = __shfl(invB, ql);
      float vA0 = s0a * oa0[r] + s1a * sm_o[qsub][r * 64 + lane];
      float vA1 = s0a * oa1[r] + s1a * sm_o[qsub][(16 + r) * 64 + lane];
      float vB0 = s0b * ob0[r] + s1b * sm_o[qsub][(32 + r) * 64 + lane];
      float vB1 = s0b * ob1[r] + s1b * sm_o[qsub][(48 + r) * 64 + lane];
      size_t baseA =
          (((size_t)(b * 2048 + qbase + ql)) << 10) + h * 64 + r31;
      size_t baseB = baseA + (32ull << 10);
      ctx[baseA] = (bf16)(vA0 * iA);
      ctx[baseA + 32] = (bf16)(vA1 * iA);
      ctx[baseB] = (bf16)(vB0 * iB);
      ctx[baseB + 32] = (bf16)(vB1 * iB);
    }
  }
}

// ---------------------------------------------------------------------------
extern "C" void kernel_launch(void* const* d_in, const int* in_sizes, int n_in,
                              void* d_out, int out_size, void* d_ws, size_t ws_size,
                              hipStream_t stream) {
  const float* x  = (const float*)d_in[0];
  const float* Wq = (const float*)d_in[1];
  const float* bq = (const float*)d_in[2];
  const float* Wk = (const float*)d_in[3];
  const float* bk = (const float*)d_in[4];
  const float* Wv = (const float*)d_in[5];
  const float* bv = (const float*)d_in[6];
  const float* Wo = (const float*)d_in[7];
  const float* bo = (const float*)d_in[8];
  float* out = (float*)d_out;
  char* ws = (char*)d_ws;

  bf16* xb  = (bf16*)(ws + XB_OFF);
  bf16* wt  = (bf16*)(ws + WT_OFF);
  bf16* Qb  = (bf16*)(ws + Q_OFF);
  bf16* Kb  = (bf16*)(ws + K_OFF);
  bf16* Vb  = (bf16*)(ws + V_OFF);
  bf16* cx  = (bf16*)(ws + CTX_OFF);
  bf16* Vtb = (bf16*)(ws + XB_OFF);  // reuse xb region after gemm0

  cvt_x<<<4096, 256, 0, stream>>>(x, xb);
  cvt_w<<<dim3(16, 16, 4), 256, 0, stream>>>(Wq, Wk, Wv, Wo, wt);
  gemm_bt<0><<<dim3(64, 24), 256, 0, stream>>>(xb, wt, bq, bk, bv,
                                               Qb, Kb, Vb, nullptr);
  vtr<<<dim3(32, 64), 256, 0, stream>>>(Vb, Vtb);
  attn<<<1024, 256, 0, stream>>>(Qb, Kb, Vtb, cx);
  gemm_bt<1><<<dim3(64, 8), 256, 0, stream>>>(cx, wt + 3ull * 1024 * 1024, bo,
                                              nullptr, nullptr, nullptr,
                                              nullptr, nullptr, out);
}

// Round 8
// 195.967 us; speedup vs baseline: 4.0850x; 1.1200x over previous
//
#include <hip/hip_runtime.h>
#include <hip/hip_bf16.h>
#include <stdint.h>

// ---------------------------------------------------------------------------
// MHA forward, bf16 MFMA pipeline.
//   x[4,2048,1024] fp32; Wq/Wk/Wv/Wo [1024,1024] fp32; biases fp32.
//   out [4,2048,1024] fp32.
// ws layout (bytes):
//   [0,16M)   xb   : x as bf16 [8192][1024]  -> REUSED as Vt after gemm0
//   [16M,24M) wt   : Wq^T,Wk^T,Wv^T,Wo^T bf16, each [1024][1024]
//   [24M,40M) Qbh  : [64][2048][64] bf16 (scaled by 0.125*log2e)
//   [40M,56M) Kbh  : [64][2048][64] bf16
//   [56M,72M) Vbh  : [64][2048][64] bf16
//   [72M,88M) ctx  : [8192][1024] bf16
// Vt: [64 bh][64 d][2048 s'] bf16, s' = s with bits 2<->3 swapped.
//
// attn (round 8): R7 post-mortem — total regs = 120 VGPR + ~64 acc = 184 >
// 128 -> HW caps 2 waves/SIMD regardless of launch shape (R4/R6/R7 all ~20%
// occupancy, 37% VALUBusy, ~148us). Fix: QBLK=32/wave (acc 32 + Q 16 + s 16),
// 4 waves/block on one 128-row q-tile, K/V staged to LDS ONCE per block
// (shared; same reuse as R7) via global_load_lds with pre-swizzled source
// (gemm_bt's proven pattern). l_vec per-slot row-sum kills the per-iter
// reduce chain. launch_bounds(256,4) pins 128 VGPR -> 4 waves/SIMD.
// ---------------------------------------------------------------------------

typedef __bf16 bf16;
typedef __bf16 bf16x8 __attribute__((ext_vector_type(8)));
typedef float  f32x4  __attribute__((ext_vector_type(4)));
typedef float  f32x8  __attribute__((ext_vector_type(8)));
typedef float  f32x16 __attribute__((ext_vector_type(16)));

#define XB_OFF   (0ull)
#define WT_OFF   (16ull << 20)
#define Q_OFF    (24ull << 20)
#define K_OFF    (40ull << 20)
#define V_OFF    (56ull << 20)
#define CTX_OFF  (72ull << 20)

// 1/sqrt(64) * log2(e), folded into Q so softmax uses exp2 directly.
#define QSCALE 0.18033688011112042591f

__device__ __forceinline__ void gload_lds16(const void* g, void* l) {
  __builtin_amdgcn_global_load_lds(
      (const __attribute__((address_space(1))) void*)g,
      (__attribute__((address_space(3))) void*)l, 16, 0, 0);
}

// --------------------------- fp32 -> bf16 x --------------------------------
__global__ __launch_bounds__(256) void cvt_x(const float* __restrict__ x,
                                             bf16* __restrict__ xb) {
  int i = blockIdx.x * 256 + threadIdx.x;          // one thread = 8 elements
  const float4* p = (const float4*)x;
  float4 a = p[(size_t)i * 2];
  float4 b = p[(size_t)i * 2 + 1];
  bf16x8 o;
  o[0] = (bf16)a.x; o[1] = (bf16)a.y; o[2] = (bf16)a.z; o[3] = (bf16)a.w;
  o[4] = (bf16)b.x; o[5] = (bf16)b.y; o[6] = (bf16)b.z; o[7] = (bf16)b.w;
  *((bf16x8*)xb + i) = o;
}

// ------------------- weight transpose + convert (W^T bf16) -----------------
__global__ __launch_bounds__(256) void cvt_w(const float* __restrict__ w0,
                                             const float* __restrict__ w1,
                                             const float* __restrict__ w2,
                                             const float* __restrict__ w3,
                                             bf16* __restrict__ wt) {
  int z = blockIdx.z;
  const float* W = (z == 0) ? w0 : (z == 1) ? w1 : (z == 2) ? w2 : w3;
  bf16* Wt = wt + (size_t)z * 1024 * 1024;
  __shared__ float tile[64][65];
  int i0 = blockIdx.y * 64, o0 = blockIdx.x * 64;
  int tid = threadIdx.x;
#pragma unroll
  for (int rep = 0; rep < 16; rep++) {
    int idx = rep * 256 + tid;
    int r = idx >> 6, c = idx & 63;
    tile[r][c] = W[(size_t)(i0 + r) * 1024 + o0 + c];
  }
  __syncthreads();
#pragma unroll
  for (int rep = 0; rep < 16; rep++) {
    int idx = rep * 256 + tid;
    int r = idx >> 6, c = idx & 63;
    Wt[(size_t)(o0 + r) * 1024 + i0 + c] = (bf16)tile[c][r];
  }
}

// --------------------------- NT bf16 GEMM ----------------------------------
// C[M,N] = A[M,1024] * Bt[N,1024]^T (+bias).  128x128 tile, BK=64, 4 waves.
// MODE 0: N=3072 fused QKV -> scatter to Qbh/Kbh/Vbh (Q scaled).
// MODE 1: N=1024 out-proj -> fp32 out.
template <int MODE>
__global__ __launch_bounds__(256, 2) void gemm_bt(
    const bf16* __restrict__ A, const bf16* __restrict__ Bt,
    const float* __restrict__ b0, const float* __restrict__ b1,
    const float* __restrict__ b2,
    bf16* __restrict__ Qo, bf16* __restrict__ Ko, bf16* __restrict__ Vo,
    float* __restrict__ out) {
  __shared__ __align__(16) bf16 a_lds[128 * 64];
  __shared__ __align__(16) bf16 b_lds[128 * 64];
  int tid = threadIdx.x;
  int lane = tid & 63, wid = tid >> 6;
  int wr = wid >> 1, wc = wid & 1;
  int g = lane >> 4, rlo = lane & 15;
  int m0 = blockIdx.x * 128, n0 = blockIdx.y * 128;

  f32x4 acc[4][4] = {};
  const char* Ab = (const char*)A;
  const char* Bb = (const char*)Bt;

  for (int k0 = 0; k0 < 1024; k0 += 64) {
#pragma unroll
    for (int rep = 0; rep < 4; rep++) {
      int idx = rep * 256 + tid;
      int row = idx >> 3;
      int sw = ((idx & 7) * 16) ^ ((row & 7) << 4);
      gload_lds16(Ab + ((size_t)(m0 + row) * 1024 + k0) * 2 + sw,
                  (char*)a_lds + (size_t)idx * 16);
    }
#pragma unroll
    for (int rep = 0; rep < 4; rep++) {
      int idx = rep * 256 + tid;
      int row = idx >> 3;
      int sw = ((idx & 7) * 16) ^ ((row & 7) << 4);
      gload_lds16(Bb + ((size_t)(n0 + row) * 1024 + k0) * 2 + sw,
                  (char*)b_lds + (size_t)idx * 16);
    }
    __syncthreads();
#pragma unroll
    for (int ks = 0; ks < 2; ks++) {
      bf16x8 af[4], bfr[4];
#pragma unroll
      for (int mt = 0; mt < 4; mt++) {
        int row = wr * 64 + mt * 16 + rlo;
        int koff = (ks * 32 + g * 8) ^ ((row & 7) << 3);
        af[mt] = *(const bf16x8*)&a_lds[row * 64 + koff];
      }
#pragma unroll
      for (int nt = 0; nt < 4; nt++) {
        int row = wc * 64 + nt * 16 + rlo;
        int koff = (ks * 32 + g * 8) ^ ((row & 7) << 3);
        bfr[nt] = *(const bf16x8*)&b_lds[row * 64 + koff];
      }
#pragma unroll
      for (int mt = 0; mt < 4; mt++)
#pragma unroll
        for (int nt = 0; nt < 4; nt++)
          acc[mt][nt] = __builtin_amdgcn_mfma_f32_16x16x32_bf16(
              af[mt], bfr[nt], acc[mt][nt], 0, 0, 0);
    }
    __syncthreads();
  }

#pragma unroll
  for (int nt = 0; nt < 4; nt++) {
    int n = n0 + wc * 64 + nt * 16 + rlo;
    if (MODE == 0) {
      int which = n >> 10, nn = n & 1023;
      const float* bp = (which == 0) ? b0 : (which == 1) ? b1 : b2;
      float bias = bp[nn];
      bf16* dst = (which == 0) ? Qo : (which == 1) ? Ko : Vo;
      float scale = (which == 0) ? QSCALE : 1.0f;
      int h = nn >> 6, hd = nn & 63;
#pragma unroll
      for (int mt = 0; mt < 4; mt++) {
#pragma unroll
        for (int r = 0; r < 4; r++) {
          int m = m0 + wr * 64 + mt * 16 + g * 4 + r;
          int bb = m >> 11, ss = m & 2047;
          float v = (acc[mt][nt][r] + bias) * scale;
          dst[(((size_t)(bb * 16 + h) * 2048 + ss) << 6) + hd] = (bf16)v;
        }
      }
    } else {
      float bias = b0[n];
#pragma unroll
      for (int mt = 0; mt < 4; mt++) {
#pragma unroll
        for (int r = 0; r < 4; r++) {
          int m = m0 + wr * 64 + mt * 16 + g * 4 + r;
          out[(size_t)m * 1024 + n] = acc[mt][nt][r] + bias;
        }
      }
    }
  }
}

// ----------------- V transpose with sigma permutation baked ----------------
// Vt[bh][d][s'] = V[bh][sigma(s')][d], sigma = swap bits 2<->3 (self-inverse).
__global__ __launch_bounds__(256) void vtr(const bf16* __restrict__ V,
                                           bf16* __restrict__ Vt) {
  __shared__ bf16 t[64][72];
  int bh = blockIdx.y, s0 = blockIdx.x * 64;
  int tid = threadIdx.x;
  const bf16* Vb = V + ((size_t)bh * 2048 + s0) * 64;
  bf16* Tb = Vt + (size_t)bh * 64 * 2048;
#pragma unroll
  for (int rep = 0; rep < 2; rep++) {
    int idx = rep * 256 + tid;
    int s = idx >> 3, dv = (idx & 7) * 8;
    bf16x8 v = *(const bf16x8*)&Vb[(size_t)s * 64 + dv];
#pragma unroll
    for (int j = 0; j < 8; j++) t[s][dv + j] = v[j];
  }
  __syncthreads();
#pragma unroll
  for (int rep = 0; rep < 2; rep++) {
    int idx = rep * 256 + tid;
    int d = idx >> 3, sc = (idx & 7) * 8;
    bf16x8 v;
#pragma unroll
    for (int j = 0; j < 8; j++) {
      int sl = sc + j;
      int sp = (sl & ~12) | ((sl & 4) << 1) | ((sl & 8) >> 1);  // sigma
      v[j] = t[sp][d];
    }
    *(bf16x8*)&Tb[(size_t)d * 2048 + s0 + sc] = v;
  }
}

// --------------------------- flash attention --------------------------------
// grid: 1024 x 256 threads. 4 waves/block; block owns (bh, 128-row q-tile);
// wave w owns q-subtile of 32 rows; ALL waves sweep t=0..2047 together,
// sharing K/V tiles staged in LDS (double-buffered, global_load_lds with
// pre-swizzled source; 128B rows, XOR key (row&7)<<4 — gemm_bt's pattern).
// Swapped QK^T (mfma(K,Q)) -> lane owns one q-row. l_vec: per-slot row-sum
// accumulated without any per-iter reduce; single tree+shfl at the end.
// Register budget: Q 16 + acc 32 + s 16 + lvec 8 + temps ~= 116 -> pinned
// to 128 via launch_bounds(256,4) => 4 waves/SIMD (R7 was reg-capped at 2).
__global__ __launch_bounds__(256, 4) void attn(const bf16* __restrict__ Q,
                                               const bf16* __restrict__ K,
                                               const bf16* __restrict__ Vt,
                                               bf16* __restrict__ ctx) {
  // K tile: [32 t][64 d] = 128B rows. V tile: [64 d][64 slots] (32 t' used,
  // rows padded to 128B so the (row&7)<<4 swizzle stays in-row).
  __shared__ __align__(16) bf16 kbuf[2][32 * 64];
  __shared__ __align__(16) bf16 vbuf[2][64 * 64];
  int tid = threadIdx.x;
  int lane = tid & 63, wid = tid >> 6;
  int r31 = lane & 31, half = lane >> 5;
  // XCD-affine swizzle: XCD c handles bh in [c*8,(c+1)*8): 4MB KV per L2.
  int wg = blockIdx.x;
  int virt = (wg & 7) * 128 + (wg >> 3);
  int bh = virt >> 4, qt = virt & 15;
  int qbase = qt * 128 + wid * 32;

  const char* Kg = (const char*)(K + (size_t)bh * 2048 * 64);
  const char* Vg = (const char*)(Vt + (size_t)bh * 64 * 2048);

  // ---- staging lane constants (source pre-swizzled; LDS dest linear) ----
  int srow = (lane >> 3);        // 0..7 (row within this wave's 8-row slab)
  int schunk = lane & 7;         // 16B chunk index within 128B row
  int kt = wid * 8 + srow;                         // K row 0..31
  int ksrc = ((schunk ^ srow) << 4);               // kt&7 == srow
  int vd = wid * 8 + srow;                         // V row (d) 0..31 per inst
  int vsrc = (((schunk ^ srow) & 3) << 4);         // valid chunks 0..3, dup pad

  // ---- per-lane LDS read offsets (elements) ----
  int rofs[4];
#pragma unroll
  for (int ks = 0; ks < 4; ks++)
    rofs[ks] = r31 * 64 + (((2 * ks + half) ^ (r31 & 7)) << 3);

  // ---- Q fragments (global, once; L2-resident) ----
  const bf16* qrow = Q + ((size_t)bh * 2048 + qbase + r31) * 64 + half * 8;
  bf16x8 qa[4];
#pragma unroll
  for (int ks = 0; ks < 4; ks++) qa[ks] = *(const bf16x8*)&qrow[ks * 16];

  f32x16 o0 = {}, o1 = {};
  f32x8 lvec = {};
  float m = -1e30f;

#define STAGE(BUF, T0)                                                        \
  do {                                                                        \
    gload_lds16(Kg + ((size_t)((T0) + kt) << 7) + ksrc,                      \
                (char*)kbuf[BUF] + tid * 16);                                 \
    gload_lds16(Vg + ((size_t)vd << 12) + (T0) * 2 + vsrc,                   \
                (char*)vbuf[BUF] + tid * 16);                                 \
    gload_lds16(Vg + ((size_t)(vd + 32) << 12) + (T0) * 2 + vsrc,            \
                (char*)vbuf[BUF] + 4096 + tid * 16);                          \
  } while (0)

  STAGE(0, 0);
  __syncthreads();

  int cur = 0;
  for (int it = 0; it < 64; ++it) {
    // prefetch next tile into the other buffer (in flight across compute)
    STAGE(cur ^ 1, ((it + 1) & 63) * 32);

    const bf16* kb = kbuf[cur];
    const bf16* vb = vbuf[cur];

    // QK^T: S^T[t][q], col = lane&31 = q, row t = (reg&3)+8*(reg>>2)+4*half
    f32x16 s = {};
    __builtin_amdgcn_s_setprio(1);
#pragma unroll
    for (int ks = 0; ks < 4; ks++) {
      bf16x8 kf = *(const bf16x8*)&kb[rofs[ks]];
      s = __builtin_amdgcn_mfma_f32_32x32x16_bf16(kf, qa[ks], s, 0, 0, 0);
    }
    __builtin_amdgcn_s_setprio(0);

    // V fragments (independent of softmax; compiler schedules early)
    bf16x8 v00 = *(const bf16x8*)&vb[rofs[0]];
    bf16x8 v01 = *(const bf16x8*)&vb[rofs[1]];
    bf16x8 v10 = *(const bf16x8*)&vb[2048 + rofs[0]];
    bf16x8 v11 = *(const bf16x8*)&vb[2048 + rofs[1]];

    // ---- softmax (defer-max T13; l_vec: no per-iter reduce) ----
    float pm = fmaxf(fmaxf(fmaxf(s[0], s[1]), fmaxf(s[2], s[3])),
                     fmaxf(fmaxf(s[4], s[5]), fmaxf(s[6], s[7])));
    float pm2 = fmaxf(fmaxf(fmaxf(s[8], s[9]), fmaxf(s[10], s[11])),
                      fmaxf(fmaxf(s[12], s[13]), fmaxf(s[14], s[15])));
    pm = fmaxf(pm, pm2);
    pm = fmaxf(pm, __shfl_xor(pm, 32));
    if (!__all(pm - m <= 8.0f)) {
      float mn = fmaxf(m, pm);
      float scl = __builtin_amdgcn_exp2f(m - mn);
      m = mn;
#pragma unroll
      for (int i = 0; i < 8; i++) lvec[i] *= scl;  // lane-own row: no shfl
#pragma unroll
      for (int r = 0; r < 16; r++) {
        float sc = __shfl(scl, (r & 3) + 8 * (r >> 2) + 4 * half);
        o0[r] *= sc;
        o1[r] *= sc;
      }
    }
#pragma unroll
    for (int i = 0; i < 16; i++) s[i] = __builtin_amdgcn_exp2f(s[i] - m);
#pragma unroll
    for (int i = 0; i < 8; i++) lvec[i] += s[i] + s[i + 8];

    bf16x8 pa0, pa1;
#pragma unroll
    for (int i = 0; i < 8; i++) {
      pa0[i] = (bf16)s[i];
      pa1[i] = (bf16)s[8 + i];
    }

    __builtin_amdgcn_s_setprio(1);
    o0 = __builtin_amdgcn_mfma_f32_32x32x16_bf16(pa0, v00, o0, 0, 0, 0);
    o1 = __builtin_amdgcn_mfma_f32_32x32x16_bf16(pa0, v10, o1, 0, 0, 0);
    o0 = __builtin_amdgcn_mfma_f32_32x32x16_bf16(pa1, v01, o0, 0, 0, 0);
    o1 = __builtin_amdgcn_mfma_f32_32x32x16_bf16(pa1, v11, o1, 0, 0, 0);
    __builtin_amdgcn_s_setprio(0);

    __syncthreads();  // drains staging (vmcnt0) + read/write hazard fence
    cur ^= 1;
  }
#undef STAGE

  // ---- final row-sum reduce (once) + epilogue ----
  float l = (((lvec[0] + lvec[1]) + (lvec[2] + lvec[3])) +
             ((lvec[4] + lvec[5]) + (lvec[6] + lvec[7])));
  l += __shfl_xor(l, 32);
  float inv = 1.0f / l;
  int b = bh >> 4, h = bh & 15;
#pragma unroll
  for (int r = 0; r < 16; r++) {
    int ql = (r & 3) + 8 * (r >> 2) + 4 * half;
    float iv = __shfl(inv, ql);
    size_t base = (((size_t)(b * 2048 + qbase + ql)) << 10) + h * 64 + r31;
    ctx[base] = (bf16)(o0[r] * iv);
    ctx[base + 32] = (bf16)(o1[r] * iv);
  }
}

// ---------------------------------------------------------------------------
extern "C" void kernel_launch(void* const* d_in, const int* in_sizes, int n_in,
                              void* d_out, int out_size, void* d_ws, size_t ws_size,
                              hipStream_t stream) {
  const float* x  = (const float*)d_in[0];
  const float* Wq = (const float*)d_in[1];
  const float* bq = (const float*)d_in[2];
  const float* Wk = (const float*)d_in[3];
  const float* bk = (const float*)d_in[4];
  const float* Wv = (const float*)d_in[5];
  const float* bv = (const float*)d_in[6];
  const float* Wo = (const float*)d_in[7];
  const float* bo = (const float*)d_in[8];
  float* out = (float*)d_out;
  char* ws = (char*)d_ws;

  bf16* xb  = (bf16*)(ws + XB_OFF);
  bf16* wt  = (bf16*)(ws + WT_OFF);
  bf16* Qb  = (bf16*)(ws + Q_OFF);
  bf16* Kb  = (bf16*)(ws + K_OFF);
  bf16* Vb  = (bf16*)(ws + V_OFF);
  bf16* cx  = (bf16*)(ws + CTX_OFF);
  bf16* Vtb = (bf16*)(ws + XB_OFF);  // reuse xb region after gemm0

  cvt_x<<<4096, 256, 0, stream>>>(x, xb);
  cvt_w<<<dim3(16, 16, 4), 256, 0, stream>>>(Wq, Wk, Wv, Wo, wt);
  gemm_bt<0><<<dim3(64, 24), 256, 0, stream>>>(xb, wt, bq, bk, bv,
                                               Qb, Kb, Vb, nullptr);
  vtr<<<dim3(32, 64), 256, 0, stream>>>(Vb, Vtb);
  attn<<<1024, 256, 0, stream>>>(Qb, Kb, Vtb, cx);
  gemm_bt<1><<<dim3(64, 8), 256, 0, stream>>>(cx, wt + 3ull * 1024 * 1024, bo,
                                              nullptr, nullptr, nullptr,
                                              nullptr, nullptr, out);
}